// Round 1
// baseline (812.092 us; speedup 1.0000x reference)
//
#include <hip/hip_runtime.h>

// Rz phase layer: out = exp(-0.5i*phase[k][d]) * (re + i*im)
// BATCH=256, N_BLOCKS=32, DC=2, N_QUBITS=12, DIM=4096
//
// V2: split into (A) tiny table-build kernel writing the 32x4096 (cos,sin)
// table (1 MB) into d_ws, and (B) a pure streaming FMA kernel that reads the
// L2-resident table. Removes all transcendental + bit-reduction work from the
// hot kernel so it is structurally a copy (same shape as the 6.2 TB/s fills).
#define NQ     12
#define DIM    4096
#define NB     32
#define TOTAL  67108864   // elements per plane (re / im)
#define N4     16777216   // TOTAL / 4
#define TAB4   32768      // NB * DIM/4 float4-groups in the table

typedef float v4f __attribute__((ext_vector_type(4)));

// Kernel A: build U table. Layout: tab[2*(k*1024+d4)]   = (c0,s0,c1,s1)
//                                  tab[2*(k*1024+d4)+1] = (c2,s2,c3,s3)
// for the 4 consecutive dims d0..d0+3 of group d4 in circuit block k.
__global__ __launch_bounds__(256) void rz_table_kernel(
        const float* __restrict__ w, v4f* __restrict__ tab) {
    int t = blockIdx.x * blockDim.x + threadIdx.x;   // 0..32767
    int k  = t >> 10;                                // block index
    int d4 = t & 1023;
    int d0 = d4 << 2;
    const float* wk = w + k * NQ;                    // weights (1,32,1,12,1)
    float h = 0.f;
#pragma unroll
    for (int q = 0; q < 10; ++q) {
        float wq = wk[q];
        h += ((d0 >> (NQ - 1 - q)) & 1) ? -wq : wq;
    }
    float w10 = wk[10], w11 = wk[11];
    // j = 0..3 : qubit10 bit = (j>>1)&1, qubit11 bit = j&1 ; sign + if bit==0
    float c0, s0, c1, s1, c2, s2, c3, s3;
    __sincosf(0.5f * (h + w10 + w11), &s0, &c0);
    __sincosf(0.5f * (h + w10 - w11), &s1, &c1);
    __sincosf(0.5f * (h - w10 + w11), &s2, &c2);
    __sincosf(0.5f * (h - w10 - w11), &s3, &c3);
    v4f cs01, cs23;
    cs01.x = c0; cs01.y = s0; cs01.z = c1; cs01.w = s1;
    cs23.x = c2; cs23.y = s2; cs23.z = c3; cs23.w = s3;
    tab[2 * t]     = cs01;
    tab[2 * t + 1] = cs23;
}

// Kernel B: pure stream. out_re = c*re + s*im ; out_im = c*im - s*re
__global__ __launch_bounds__(256) void rz_stream_kernel(
        const v4f* __restrict__ re, const v4f* __restrict__ im,
        const v4f* __restrict__ tab,
        v4f* __restrict__ outr, v4f* __restrict__ outi) {
    int i = blockIdx.x * blockDim.x + threadIdx.x;
    int r  = i >> 10;                 // row = (b*32 + k)*2 + c
    int k  = (r >> 1) & 31;           // circuit block (wave-uniform)
    int d4 = i & 1023;
    int t  = (k << 10) | d4;
    // cached loads: table is 1 MB, L2/L3-resident, reused 512x
    v4f cs01 = tab[2 * t];
    v4f cs23 = tab[2 * t + 1];
    v4f a = __builtin_nontemporal_load(re + i);
    v4f b = __builtin_nontemporal_load(im + i);
    v4f orv, oiv;
    orv.x = cs01.x * a.x + cs01.y * b.x;  oiv.x = cs01.x * b.x - cs01.y * a.x;
    orv.y = cs01.z * a.y + cs01.w * b.y;  oiv.y = cs01.z * b.y - cs01.w * a.y;
    orv.z = cs23.x * a.z + cs23.y * b.z;  oiv.z = cs23.x * b.z - cs23.y * a.z;
    orv.w = cs23.z * a.w + cs23.w * b.w;  oiv.w = cs23.z * b.w - cs23.w * a.w;
    __builtin_nontemporal_store(orv, outr + i);
    __builtin_nontemporal_store(oiv, outi + i);
}

extern "C" void kernel_launch(void* const* d_in, const int* in_sizes, int n_in,
                              void* d_out, int out_size, void* d_ws, size_t ws_size,
                              hipStream_t stream) {
    const v4f* re = (const v4f*)d_in[0];
    const v4f* im = (const v4f*)d_in[1];
    const float* w = (const float*)d_in[2];
    v4f* outr = (v4f*)d_out;
    v4f* outi = outr + N4;            // plane 1: imag
    v4f* tab  = (v4f*)d_ws;           // 1 MB table in workspace

    rz_table_kernel<<<TAB4 / 256, 256, 0, stream>>>(w, tab);
    rz_stream_kernel<<<N4 / 256, 256, 0, stream>>>(re, im, tab, outr, outi);
}